// Round 6
// baseline (577.316 us; speedup 1.0000x reference)
//
#include <hip/hip_runtime.h>
#include <math.h>

#define B_ 4
#define S_ 2048
#define D_ 1280
#define H_ 16
#define HD_ 80
#define HHD (H_ * HD_)        // 1280
#define QKVN (3 * H_ * HD_)   // 3840

typedef __bf16 bf16x8 __attribute__((ext_vector_type(8)));
typedef float  f32x4  __attribute__((ext_vector_type(4)));

// ---------------------------------------------------------------------------
// fp32 -> bf16 bulk convert
// ---------------------------------------------------------------------------
__global__ __launch_bounds__(256) void cvt_bf16(
    const float* __restrict__ in, __bf16* __restrict__ out, int n8)
{
    const int i = blockIdx.x * 256 + threadIdx.x;
    if (i < n8) {
        const float4 a = ((const float4*)in)[2 * (size_t)i];
        const float4 b = ((const float4*)in)[2 * (size_t)i + 1];
        bf16x8 v = {(__bf16)a.x, (__bf16)a.y, (__bf16)a.z, (__bf16)a.w,
                    (__bf16)b.x, (__bf16)b.y, (__bf16)b.z, (__bf16)b.w};
        *(bf16x8*)(out + 8 * (size_t)i) = v;
    }
}

// ---------------------------------------------------------------------------
// bf16 MFMA GEMM core (m97 structure, R4-verified)
// ---------------------------------------------------------------------------
__device__ __forceinline__ void async_copy16(const void* g, void* l)
{
    __builtin_amdgcn_global_load_lds(
        (const __attribute__((address_space(1))) unsigned int*)g,
        (__attribute__((address_space(3))) unsigned int*)l, 16, 0, 0);
}

__device__ __forceinline__ void stage128x64(
    const __bf16* __restrict__ src, int K, char* lds, int tid)
{
    const int wave = tid >> 6, lane = tid & 63;
#pragma unroll
    for (int i = 0; i < 4; ++i) {
        const int c = (wave * 4 + i) * 64 + lane;
        const int r = c >> 3;
        const int g = (c & 7) ^ (r & 7);
        async_copy16(src + (size_t)r * K + g * 8, lds + (wave * 4 + i) * 1024);
    }
}

__device__ __forceinline__ bf16x8 frag_ld(const char* lds, int m, int j)
{
    return *(const bf16x8*)(lds + m * 128 + ((j ^ (m & 7)) << 4));
}

__device__ __forceinline__ void mfma_loop(
    const __bf16* __restrict__ A, const __bf16* __restrict__ W, int K,
    char* ldsA, char* ldsB, int tid, f32x4 acc[4][4])
{
    const int wave = tid >> 6;
    const int wm = wave >> 1, wn = wave & 1;
    const int l16 = tid & 15, quad = (tid & 63) >> 4;

#pragma unroll
    for (int mi = 0; mi < 4; ++mi)
#pragma unroll
        for (int ni = 0; ni < 4; ++ni) acc[mi][ni] = (f32x4){0.f, 0.f, 0.f, 0.f};

    for (int k0 = 0; k0 < K; k0 += 64) {
        __syncthreads();
        stage128x64(A + k0, K, ldsA, tid);
        stage128x64(W + k0, K, ldsB, tid);
        __syncthreads();
#pragma unroll
        for (int ks = 0; ks < 2; ++ks) {
            bf16x8 af[4], bfr[4];
#pragma unroll
            for (int mi = 0; mi < 4; ++mi)
                af[mi] = frag_ld(ldsA, wm * 64 + mi * 16 + l16, ks * 4 + quad);
#pragma unroll
            for (int ni = 0; ni < 4; ++ni)
                bfr[ni] = frag_ld(ldsB, wn * 64 + ni * 16 + l16, ks * 4 + quad);
#pragma unroll
            for (int mi = 0; mi < 4; ++mi)
#pragma unroll
                for (int ni = 0; ni < 4; ++ni)
                    acc[mi][ni] = __builtin_amdgcn_mfma_f32_16x16x32_bf16(
                        af[mi], bfr[ni], acc[mi][ni], 0, 0, 0);
        }
    }
}

// ---------------------------------------------------------------------------
// QKV GEMM + fused epilogue. Q scale now folds an EXTRA log2(e) so attention
// softmax runs in exp2 domain: exp(s-m) == exp2(s'-m') with s' = log2e*s.
// ---------------------------------------------------------------------------
__global__ __launch_bounds__(256) void gemm_qkv_mfma(
    const __bf16* __restrict__ Ab, const __bf16* __restrict__ Wb,
    const float* __restrict__ bias, const float* __restrict__ scaling,
    __bf16* __restrict__ Qb, __bf16* __restrict__ Kb, __bf16* __restrict__ Vtb)
{
    __shared__ __align__(16) char ldsA[128 * 128];
    __shared__ __align__(16) char ldsB[128 * 128];
    const int tid = threadIdx.x;
    const int m0 = blockIdx.y * 128, n0 = blockIdx.x * 128;

    f32x4 acc[4][4];
    mfma_loop(Ab + (size_t)m0 * D_, Wb + (size_t)n0 * D_, D_, ldsA, ldsB, tid, acc);

    const int wave = tid >> 6, wm = wave >> 1, wn = wave & 1;
    const int l16 = tid & 15, quad = (tid & 63) >> 4;
    const int sec = n0 / HHD;

#pragma unroll
    for (int ni = 0; ni < 4; ++ni) {
        const int col = n0 + wn * 64 + ni * 16 + l16;
        const int cis = col - sec * HHD;
        const int h = cis / HD_;
        const int d = cis - h * HD_;
        const float bv = bias[col];
        float qsv = 0.f;
        if (sec == 0)   // softplus * log2e/sqrt(80) * extra log2e (exp2 domain)
            qsv = log1pf(expf(scaling[d])) *
                  (1.442695041f * 1.442695041f / 8.944271910f);
#pragma unroll
        for (int mi = 0; mi < 4; ++mi) {
#pragma unroll
            for (int r = 0; r < 4; ++r) {
                const int row = m0 + wm * 64 + mi * 16 + quad * 4 + r;
                const int bb = row >> 11;
                const int s = row & (S_ - 1);
                const size_t bh = (size_t)(bb * H_ + h);
                const float v = acc[mi][ni][r] + bv;
                if (sec == 0)      Qb[(bh * S_ + s) * HD_ + d] = (__bf16)(v * qsv);
                else if (sec == 1) Kb[(bh * S_ + s) * HD_ + d] = (__bf16)v;
                else               Vtb[(bh * HD_ + d) * S_ + s] = (__bf16)v;
            }
        }
    }
}

// ---------------------------------------------------------------------------
// Output-projection GEMM (R4-verified)
// ---------------------------------------------------------------------------
__global__ __launch_bounds__(256) void gemm_o_mfma(
    const __bf16* __restrict__ Ab, const __bf16* __restrict__ Wb,
    const float* __restrict__ bias, float* __restrict__ C)
{
    __shared__ __align__(16) char ldsA[128 * 128];
    __shared__ __align__(16) char ldsB[128 * 128];
    const int tid = threadIdx.x;
    const int m0 = blockIdx.y * 128, n0 = blockIdx.x * 128;

    f32x4 acc[4][4];
    mfma_loop(Ab + (size_t)m0 * D_, Wb + (size_t)n0 * D_, D_, ldsA, ldsB, tid, acc);

    const int wave = tid >> 6, wm = wave >> 1, wn = wave & 1;
    const int l16 = tid & 15, quad = (tid & 63) >> 4;

#pragma unroll
    for (int ni = 0; ni < 4; ++ni) {
        const int col = n0 + wn * 64 + ni * 16 + l16;
        const float bv = bias[col];
#pragma unroll
        for (int mi = 0; mi < 4; ++mi) {
#pragma unroll
            for (int r = 0; r < 4; ++r) {
                const int row = m0 + wm * 64 + mi * 16 + quad * 4 + r;
                C[(size_t)row * D_ + col] = acc[mi][ni][r] + bv;
            }
        }
    }
}

// ---------------------------------------------------------------------------
// 16-lane DPP reductions (R5-verified)
// ---------------------------------------------------------------------------
template<int CTRL>
__device__ __forceinline__ float dppmov(float v)
{
    return __builtin_bit_cast(float,
        __builtin_amdgcn_update_dpp(0, __builtin_bit_cast(int, v),
                                    CTRL, 0xf, 0xf, true));
}
__device__ __forceinline__ float rmax16(float v)
{
    v = fmaxf(v, dppmov<0xB1>(v));
    v = fmaxf(v, dppmov<0x4E>(v));
    v = fmaxf(v, dppmov<0x141>(v));
    v = fmaxf(v, dppmov<0x140>(v));
    return v;
}
__device__ __forceinline__ float rsum16(float v)
{
    v += dppmov<0xB1>(v);
    v += dppmov<0x4E>(v);
    v += dppmov<0x141>(v);
    v += dppmov<0x140>(v);
    return v;
}

// ---------------------------------------------------------------------------
// Causal flash attention v6: paired q-tiles {x, 31-x}, BK=64 keys/iteration
// (4 key-subtiles), exp2-domain softmax, edge-only masking, DPP reductions.
// ---------------------------------------------------------------------------
__global__ __launch_bounds__(256, 4) void attn_v6(
    const __bf16* __restrict__ Qb, const __bf16* __restrict__ Kb,
    const __bf16* __restrict__ Vtb, __bf16* __restrict__ out)
{
    __shared__ __align__(16) __bf16 Ps[4][2][16][72];   // [wave][group], 64+8 pad

    const int tid = threadIdx.x;
    const int wave = tid >> 6;
    const int lane = tid & 63;
    const int l16 = lane & 15;
    const int quad = lane >> 4;
    const int b = blockIdx.z, h = blockIdx.y;
    const int bh = b * H_ + h;
    const int x = blockIdx.x;                       // 0..15
    const int q_lo = 64 * x + 16 * wave;
    const int q_hi = 64 * (31 - x) + 16 * wave;

    const __bf16* Kbase = Kb + (size_t)bh * S_ * HD_;
    const __bf16* Vbase = Vtb + (size_t)bh * HD_ * S_;

    bf16x8 qfL[3], qfH[3];
    {
        const __bf16* QrowL = Qb + ((size_t)bh * S_ + q_lo + l16) * HD_;
        const __bf16* QrowH = Qb + ((size_t)bh * S_ + q_hi + l16) * HD_;
        qfL[0] = *(const bf16x8*)(QrowL + quad * 8);
        qfL[1] = *(const bf16x8*)(QrowL + 32 + quad * 8);
        qfH[0] = *(const bf16x8*)(QrowH + quad * 8);
        qfH[1] = *(const bf16x8*)(QrowH + 32 + quad * 8);
        bf16x8 zL = {}, zH = {};
        if (quad < 2) {
            zL = *(const bf16x8*)(QrowL + 64 + quad * 8);
            zH = *(const bf16x8*)(QrowH + 64 + quad * 8);
        }
        qfL[2] = zL; qfH[2] = zH;
    }

    float mL[4], lL[4], mH[4], lH[4];
#pragma unroll
    for (int i = 0; i < 4; ++i) { mL[i] = -1e30f; lL[i] = 0.f; mH[i] = -1e30f; lH[i] = 0.f; }
    f32x4 oL[5], oH[5];
#pragma unroll
    for (int t = 0; t < 5; ++t) { oL[t] = (f32x4){0.f,0.f,0.f,0.f}; oH[t] = (f32x4){0.f,0.f,0.f,0.f}; }

    const int nkt_lo = (q_lo + 16 + 63) >> 6;
    const int nkt_hi = (q_hi + 16 + 63) >> 6;

    for (int kt = 0; kt < nkt_hi; ++kt) {
        const int k0 = kt * 64;
        const bool do_lo = (kt < nkt_lo);           // wave-uniform

        // ---- S = Q K^T : 4 key-subtiles, shared K fragments ----
        f32x4 sH[4], sL[4];
#pragma unroll
        for (int t = 0; t < 4; ++t) {
            const __bf16* Krow = Kbase + (size_t)(k0 + t * 16 + l16) * HD_;
            const bf16x8 kf0 = *(const bf16x8*)(Krow + quad * 8);
            const bf16x8 kf1 = *(const bf16x8*)(Krow + 32 + quad * 8);
            bf16x8 kf2 = {};
            if (quad < 2) kf2 = *(const bf16x8*)(Krow + 64 + quad * 8);

            f32x4 a = (f32x4){0.f,0.f,0.f,0.f};
            a = __builtin_amdgcn_mfma_f32_16x16x32_bf16(qfH[0], kf0, a, 0, 0, 0);
            a = __builtin_amdgcn_mfma_f32_16x16x32_bf16(qfH[1], kf1, a, 0, 0, 0);
            a = __builtin_amdgcn_mfma_f32_16x16x32_bf16(qfH[2], kf2, a, 0, 0, 0);
            sH[t] = a;
            if (do_lo) {
                f32x4 c = (f32x4){0.f,0.f,0.f,0.f};
                c = __builtin_amdgcn_mfma_f32_16x16x32_bf16(qfL[0], kf0, c, 0, 0, 0);
                c = __builtin_amdgcn_mfma_f32_16x16x32_bf16(qfL[1], kf1, c, 0, 0, 0);
                c = __builtin_amdgcn_mfma_f32_16x16x32_bf16(qfL[2], kf2, c, 0, 0, 0);
                sL[t] = c;
            }
        }

        // ---- hi group softmax (exp2 domain, edge-only masking) ----
        float aH[4];
        {
            if (k0 + 63 > q_hi) {                   // wave-uniform edge tile
#pragma unroll
                for (int t = 0; t < 4; ++t)
#pragma unroll
                    for (int i = 0; i < 4; ++i)
                        sH[t][i] = (k0 + t * 16 + l16 <= q_hi + quad * 4 + i)
                                   ? sH[t][i] : -1e30f;
            }
            float mx[4], rs[4];
#pragma unroll
            for (int i = 0; i < 4; ++i)
                mx[i] = rmax16(fmaxf(fmaxf(sH[0][i], sH[1][i]),
                                     fmaxf(sH[2][i], sH[3][i])));
#pragma unroll
            for (int i = 0; i < 4; ++i) {
                const float mn = fmaxf(mH[i], mx[i]);
                aH[i] = exp2f(mH[i] - mn);
                mH[i] = mn;
                rs[i] = 0.f;
            }
#pragma unroll
            for (int t = 0; t < 4; ++t)
#pragma unroll
                for (int i = 0; i < 4; ++i) {
                    const float p = exp2f(sH[t][i] - mH[i]);
                    rs[i] += p;
                    Ps[wave][0][quad * 4 + i][t * 16 + l16] = (__bf16)p;
                }
#pragma unroll
            for (int i = 0; i < 4; ++i) lH[i] = lH[i] * aH[i] + rsum16(rs[i]);
        }

        // ---- lo group (predicated) ----
        float aL[4];
        if (do_lo) {
            if (k0 + 63 > q_lo) {
#pragma unroll
                for (int t = 0; t < 4; ++t)
#pragma unroll
                    for (int i = 0; i < 4; ++i)
                        sL[t][i] = (k0 + t * 16 + l16 <= q_lo + quad * 4 + i)
                                   ? sL[t][i] : -1e30f;
            }
            float mx[4], rs[4];
#pragma unroll
            for (int i = 0; i < 4; ++i)
                mx[i] = rmax16(fmaxf(fmaxf(sL[0][i], sL[1][i]),
                                     fmaxf(sL[2][i], sL[3][i])));
#pragma unroll
            for (int i = 0; i < 4; ++i) {
                const float mn = fmaxf(mL[i], mx[i]);
                aL[i] = exp2f(mL[i] - mn);
                mL[i] = mn;
                rs[i] = 0.f;
            }
#pragma unroll
            for (int t = 0; t < 4; ++t)
#pragma unroll
                for (int i = 0; i < 4; ++i) {
                    const float p = exp2f(sL[t][i] - mL[i]);
                    rs[i] += p;
                    Ps[wave][1][quad * 4 + i][t * 16 + l16] = (__bf16)p;
                }
#pragma unroll
            for (int i = 0; i < 4; ++i) lL[i] = lL[i] * aL[i] + rsum16(rs[i]);
        }

        asm volatile("s_waitcnt lgkmcnt(0)" ::: "memory");
        const bf16x8 pfH0 = *(const bf16x8*)&Ps[wave][0][l16][quad * 8];
        const bf16x8 pfH1 = *(const bf16x8*)&Ps[wave][0][l16][32 + quad * 8];
        const bf16x8 pfL0 = *(const bf16x8*)&Ps[wave][1][l16][quad * 8];
        const bf16x8 pfL1 = *(const bf16x8*)&Ps[wave][1][l16][32 + quad * 8];

        // ---- O updates: K=64 via two chained MFMAs, shared V fragments ----
#pragma unroll
        for (int t = 0; t < 5; ++t) {
            const __bf16* Vrow = Vbase + (size_t)(t * 16 + l16) * S_ + k0;
            const bf16x8 vf0 = *(const bf16x8*)(Vrow + quad * 8);
            const bf16x8 vf1 = *(const bf16x8*)(Vrow + 32 + quad * 8);
            f32x4 c;
#pragma unroll
            for (int i = 0; i < 4; ++i) c[i] = oH[t][i] * aH[i];
            c = __builtin_amdgcn_mfma_f32_16x16x32_bf16(pfH0, vf0, c, 0, 0, 0);
            oH[t] = __builtin_amdgcn_mfma_f32_16x16x32_bf16(pfH1, vf1, c, 0, 0, 0);
            if (do_lo) {
                f32x4 d;
#pragma unroll
                for (int i = 0; i < 4; ++i) d[i] = oL[t][i] * aL[i];
                d = __builtin_amdgcn_mfma_f32_16x16x32_bf16(pfL0, vf0, d, 0, 0, 0);
                oL[t] = __builtin_amdgcn_mfma_f32_16x16x32_bf16(pfL1, vf1, d, 0, 0, 0);
            }
        }
    }

    // ---- epilogue ----
#pragma unroll
    for (int i = 0; i < 4; ++i) {
        const float invH = 1.f / lH[i];
        const float invL = 1.f / lL[i];
        const size_t rowH = ((size_t)b * S_ + q_hi + quad * 4 + i) * HHD + h * HD_;
        const size_t rowL = ((size_t)b * S_ + q_lo + quad * 4 + i) * HHD + h * HD_;
#pragma unroll
        for (int t = 0; t < 5; ++t) {
            out[rowH + t * 16 + l16] = (__bf16)(oH[t][i] * invH);
            out[rowL + t * 16 + l16] = (__bf16)(oL[t][i] * invL);
        }
    }
}

// ---------------------------------------------------------------------------
extern "C" void kernel_launch(void* const* d_in, const int* in_sizes, int n_in,
                              void* d_out, int out_size, void* d_ws, size_t ws_size,
                              hipStream_t stream)
{
    const float* hidden  = (const float*)d_in[0];
    // d_in[1] attention_mask: exact additive causal (-1e9) — replicated
    // structurally in attn_v6 (exp underflow makes it bit-identical).
    const float* scaling = (const float*)d_in[2];
    const float* qkv_w   = (const float*)d_in[3];
    const float* qkv_b   = (const float*)d_in[4];
    const float* o_w     = (const float*)d_in[5];
    const float* o_b     = (const float*)d_in[6];
    float* out = (float*)d_out;

    const size_t N_HID = (size_t)B_ * S_ * D_;
    const size_t N_QW  = (size_t)QKVN * D_;
    const size_t N_OW  = (size_t)D_ * D_;
    const size_t NPH   = (size_t)B_ * H_ * S_ * HD_;

    __bf16* Ab    = (__bf16*)d_ws;
    __bf16* Wqb   = Ab + N_HID;
    __bf16* Wob   = Wqb + N_QW;
    __bf16* Qb    = Wob + N_OW;
    __bf16* Kb    = Qb + NPH;
    __bf16* Vtb   = Kb + NPH;
    __bf16* attnb = Vtb + NPH;

    dim3 blk(256);

    cvt_bf16<<<dim3(N_HID / 8 / 256), blk, 0, stream>>>(hidden, Ab, N_HID / 8);
    cvt_bf16<<<dim3(N_QW  / 8 / 256), blk, 0, stream>>>(qkv_w, Wqb, N_QW / 8);
    cvt_bf16<<<dim3(N_OW  / 8 / 256), blk, 0, stream>>>(o_w,   Wob, N_OW / 8);

    gemm_qkv_mfma<<<dim3(QKVN / 128, B_ * S_ / 128), blk, 0, stream>>>(
        Ab, Wqb, qkv_b, scaling, Qb, Kb, Vtb);

    attn_v6<<<dim3(16, H_, B_), blk, 0, stream>>>(Qb, Kb, Vtb, attnb);

    gemm_o_mfma<<<dim3(D_ / 128, B_ * S_ / 128), blk, 0, stream>>>(
        attnb, Wob, o_b, out);
}

// Round 7
// 537.617 us; speedup vs baseline: 1.0738x; 1.0738x over previous
//
#include <hip/hip_runtime.h>
#include <math.h>

#define B_ 4
#define S_ 2048
#define D_ 1280
#define H_ 16
#define HD_ 80
#define HHD (H_ * HD_)        // 1280
#define QKVN (3 * H_ * HD_)   // 3840

typedef __bf16 bf16x8 __attribute__((ext_vector_type(8)));
typedef __bf16 bf16x4 __attribute__((ext_vector_type(4)));
typedef float  f32x4  __attribute__((ext_vector_type(4)));

// ---------------------------------------------------------------------------
// fp32 -> bf16 bulk convert
// ---------------------------------------------------------------------------
__global__ __launch_bounds__(256) void cvt_bf16(
    const float* __restrict__ in, __bf16* __restrict__ out, int n8)
{
    const int i = blockIdx.x * 256 + threadIdx.x;
    if (i < n8) {
        const float4 a = ((const float4*)in)[2 * (size_t)i];
        const float4 b = ((const float4*)in)[2 * (size_t)i + 1];
        bf16x8 v = {(__bf16)a.x, (__bf16)a.y, (__bf16)a.z, (__bf16)a.w,
                    (__bf16)b.x, (__bf16)b.y, (__bf16)b.z, (__bf16)b.w};
        *(bf16x8*)(out + 8 * (size_t)i) = v;
    }
}

// ---------------------------------------------------------------------------
// bf16 MFMA GEMM core (m97 structure, R4-verified)
// ---------------------------------------------------------------------------
__device__ __forceinline__ void async_copy16(const void* g, void* l)
{
    __builtin_amdgcn_global_load_lds(
        (const __attribute__((address_space(1))) unsigned int*)g,
        (__attribute__((address_space(3))) unsigned int*)l, 16, 0, 0);
}

__device__ __forceinline__ void stage128x64(
    const __bf16* __restrict__ src, int K, char* lds, int tid)
{
    const int wave = tid >> 6, lane = tid & 63;
#pragma unroll
    for (int i = 0; i < 4; ++i) {
        const int c = (wave * 4 + i) * 64 + lane;
        const int r = c >> 3;
        const int g = (c & 7) ^ (r & 7);
        async_copy16(src + (size_t)r * K + g * 8, lds + (wave * 4 + i) * 1024);
    }
}

__device__ __forceinline__ bf16x8 frag_ld(const char* lds, int m, int j)
{
    return *(const bf16x8*)(lds + m * 128 + ((j ^ (m & 7)) << 4));
}

__device__ __forceinline__ void mfma_loop(
    const __bf16* __restrict__ A, const __bf16* __restrict__ W, int K,
    char* ldsA, char* ldsB, int tid, f32x4 acc[4][4])
{
    const int wave = tid >> 6;
    const int wm = wave >> 1, wn = wave & 1;
    const int l16 = tid & 15, quad = (tid & 63) >> 4;

#pragma unroll
    for (int mi = 0; mi < 4; ++mi)
#pragma unroll
        for (int ni = 0; ni < 4; ++ni) acc[mi][ni] = (f32x4){0.f, 0.f, 0.f, 0.f};

    for (int k0 = 0; k0 < K; k0 += 64) {
        __syncthreads();
        stage128x64(A + k0, K, ldsA, tid);
        stage128x64(W + k0, K, ldsB, tid);
        __syncthreads();
#pragma unroll
        for (int ks = 0; ks < 2; ++ks) {
            bf16x8 af[4], bfr[4];
#pragma unroll
            for (int mi = 0; mi < 4; ++mi)
                af[mi] = frag_ld(ldsA, wm * 64 + mi * 16 + l16, ks * 4 + quad);
#pragma unroll
            for (int ni = 0; ni < 4; ++ni)
                bfr[ni] = frag_ld(ldsB, wn * 64 + ni * 16 + l16, ks * 4 + quad);
#pragma unroll
            for (int mi = 0; mi < 4; ++mi)
#pragma unroll
                for (int ni = 0; ni < 4; ++ni)
                    acc[mi][ni] = __builtin_amdgcn_mfma_f32_16x16x32_bf16(
                        af[mi], bfr[ni], acc[mi][ni], 0, 0, 0);
        }
    }
}

// ---------------------------------------------------------------------------
// QKV GEMM + fused epilogue. Q scale folds an EXTRA log2(e): softmax in exp2
// domain. (R5/R6-verified)
// ---------------------------------------------------------------------------
__global__ __launch_bounds__(256) void gemm_qkv_mfma(
    const __bf16* __restrict__ Ab, const __bf16* __restrict__ Wb,
    const float* __restrict__ bias, const float* __restrict__ scaling,
    __bf16* __restrict__ Qb, __bf16* __restrict__ Kb, __bf16* __restrict__ Vtb)
{
    __shared__ __align__(16) char ldsA[128 * 128];
    __shared__ __align__(16) char ldsB[128 * 128];
    const int tid = threadIdx.x;
    const int m0 = blockIdx.y * 128, n0 = blockIdx.x * 128;

    f32x4 acc[4][4];
    mfma_loop(Ab + (size_t)m0 * D_, Wb + (size_t)n0 * D_, D_, ldsA, ldsB, tid, acc);

    const int wave = tid >> 6, wm = wave >> 1, wn = wave & 1;
    const int l16 = tid & 15, quad = (tid & 63) >> 4;
    const int sec = n0 / HHD;

#pragma unroll
    for (int ni = 0; ni < 4; ++ni) {
        const int col = n0 + wn * 64 + ni * 16 + l16;
        const int cis = col - sec * HHD;
        const int h = cis / HD_;
        const int d = cis - h * HD_;
        const float bv = bias[col];
        float qsv = 0.f;
        if (sec == 0)
            qsv = log1pf(expf(scaling[d])) *
                  (1.442695041f * 1.442695041f / 8.944271910f);
#pragma unroll
        for (int mi = 0; mi < 4; ++mi) {
#pragma unroll
            for (int r = 0; r < 4; ++r) {
                const int row = m0 + wm * 64 + mi * 16 + quad * 4 + r;
                const int bb = row >> 11;
                const int s = row & (S_ - 1);
                const size_t bh = (size_t)(bb * H_ + h);
                const float v = acc[mi][ni][r] + bv;
                if (sec == 0)      Qb[(bh * S_ + s) * HD_ + d] = (__bf16)(v * qsv);
                else if (sec == 1) Kb[(bh * S_ + s) * HD_ + d] = (__bf16)v;
                else               Vtb[(bh * HD_ + d) * S_ + s] = (__bf16)v;
            }
        }
    }
}

// ---------------------------------------------------------------------------
// Output-projection GEMM (R4-verified)
// ---------------------------------------------------------------------------
__global__ __launch_bounds__(256) void gemm_o_mfma(
    const __bf16* __restrict__ Ab, const __bf16* __restrict__ Wb,
    const float* __restrict__ bias, float* __restrict__ C)
{
    __shared__ __align__(16) char ldsA[128 * 128];
    __shared__ __align__(16) char ldsB[128 * 128];
    const int tid = threadIdx.x;
    const int m0 = blockIdx.y * 128, n0 = blockIdx.x * 128;

    f32x4 acc[4][4];
    mfma_loop(Ab + (size_t)m0 * D_, Wb + (size_t)n0 * D_, D_, ldsA, ldsB, tid, acc);

    const int wave = tid >> 6, wm = wave >> 1, wn = wave & 1;
    const int l16 = tid & 15, quad = (tid & 63) >> 4;

#pragma unroll
    for (int ni = 0; ni < 4; ++ni) {
        const int col = n0 + wn * 64 + ni * 16 + l16;
        const float bv = bias[col];
#pragma unroll
        for (int mi = 0; mi < 4; ++mi) {
#pragma unroll
            for (int r = 0; r < 4; ++r) {
                const int row = m0 + wm * 64 + mi * 16 + quad * 4 + r;
                C[(size_t)row * D_ + col] = acc[mi][ni][r] + bv;
            }
        }
    }
}

// ---------------------------------------------------------------------------
// Causal flash attention v7: TRANSPOSED scores. St = K·Q^T (A=K, B=Q — same
// loads as R5, operands swapped), so softmax reduces in-register over St rows
// (8 fmax/add + 2 shfl_xor) with SCALAR m/l/alpha per lane (q = l16).
// P^T -> B-layout via tiny LDS hop (2 ds_write_b64 + 1 ds_read_b128/group).
// O^T = Vt·P^T accumulated in C-layout; packed 8B epilogue stores.
// BK=32 (R5 traffic profile). Paired q-tiles {x, 31-x}. exp2 domain.
// ---------------------------------------------------------------------------
__global__ __launch_bounds__(256, 4) void attn_v7(
    const __bf16* __restrict__ Qb, const __bf16* __restrict__ Kb,
    const __bf16* __restrict__ Vtb, __bf16* __restrict__ out)
{
    __shared__ __align__(16) __bf16 Ps[4][2][16][40];   // [wave][group][q][32key+pad]

    const int tid = threadIdx.x;
    const int wave = tid >> 6;
    const int lane = tid & 63;
    const int l16 = lane & 15;
    const int quad = lane >> 4;
    const int b = blockIdx.z, h = blockIdx.y;
    const int bh = b * H_ + h;
    const int x = blockIdx.x;                       // 0..15
    const int q_lo = 64 * x + 16 * wave;
    const int q_hi = 64 * (31 - x) + 16 * wave;

    const __bf16* Kbase = Kb + (size_t)bh * S_ * HD_;
    const __bf16* Vbase = Vtb + (size_t)bh * HD_ * S_;

    // Q fragments (used as MFMA B operand: B[k=dim][n=q] == Q[q=l16][dim])
    bf16x8 qfL[3], qfH[3];
    {
        const __bf16* QrowL = Qb + ((size_t)bh * S_ + q_lo + l16) * HD_;
        const __bf16* QrowH = Qb + ((size_t)bh * S_ + q_hi + l16) * HD_;
        qfL[0] = *(const bf16x8*)(QrowL + quad * 8);
        qfL[1] = *(const bf16x8*)(QrowL + 32 + quad * 8);
        qfH[0] = *(const bf16x8*)(QrowH + quad * 8);
        qfH[1] = *(const bf16x8*)(QrowH + 32 + quad * 8);
        bf16x8 zL = {}, zH = {};
        if (quad < 2) {
            zL = *(const bf16x8*)(QrowL + 64 + quad * 8);
            zH = *(const bf16x8*)(QrowH + 64 + quad * 8);
        }
        qfL[2] = zL; qfH[2] = zH;
    }

    // scalar per-lane softmax state (q = q_g + l16)
    float mL = -1e30f, lL = 0.f, mH = -1e30f, lH = 0.f;
    f32x4 oL[5], oH[5];                             // O^T, C-layout [d][q]
#pragma unroll
    for (int t = 0; t < 5; ++t) { oL[t] = (f32x4){0.f,0.f,0.f,0.f}; oH[t] = (f32x4){0.f,0.f,0.f,0.f}; }

    const int nkt_lo = (q_lo + 16 + 31) >> 5;
    const int nkt_hi = (q_hi + 16 + 31) >> 5;

    for (int kt = 0; kt < nkt_hi; ++kt) {
        const int k0 = kt * 32;
        const bool do_lo = (kt < nkt_lo);           // wave-uniform

        // ---- St = K Q^T : 2 key-subtiles (rows=keys, cols=q) ----
        f32x4 sH[2], sL[2];
#pragma unroll
        for (int t = 0; t < 2; ++t) {
            const __bf16* Krow = Kbase + (size_t)(k0 + t * 16 + l16) * HD_;
            const bf16x8 kf0 = *(const bf16x8*)(Krow + quad * 8);
            const bf16x8 kf1 = *(const bf16x8*)(Krow + 32 + quad * 8);
            bf16x8 kf2 = {};
            if (quad < 2) kf2 = *(const bf16x8*)(Krow + 64 + quad * 8);

            f32x4 a = (f32x4){0.f,0.f,0.f,0.f};
            a = __builtin_amdgcn_mfma_f32_16x16x32_bf16(kf0, qfH[0], a, 0, 0, 0);
            a = __builtin_amdgcn_mfma_f32_16x16x32_bf16(kf1, qfH[1], a, 0, 0, 0);
            a = __builtin_amdgcn_mfma_f32_16x16x32_bf16(kf2, qfH[2], a, 0, 0, 0);
            sH[t] = a;
            if (do_lo) {
                f32x4 c = (f32x4){0.f,0.f,0.f,0.f};
                c = __builtin_amdgcn_mfma_f32_16x16x32_bf16(kf0, qfL[0], c, 0, 0, 0);
                c = __builtin_amdgcn_mfma_f32_16x16x32_bf16(kf1, qfL[1], c, 0, 0, 0);
                c = __builtin_amdgcn_mfma_f32_16x16x32_bf16(kf2, qfL[2], c, 0, 0, 0);
                sL[t] = c;
            }
        }

        // ---- hi group: edge mask + scalar online softmax ----
        float aH;
        {
            if (k0 + 31 > q_hi) {                   // wave-uniform edge tile
#pragma unroll
                for (int t = 0; t < 2; ++t)
#pragma unroll
                    for (int i = 0; i < 4; ++i)
                        sH[t][i] = (k0 + t * 16 + quad * 4 + i <= q_hi + l16)
                                   ? sH[t][i] : -1e30f;
            }
            float mx = sH[0][0];
#pragma unroll
            for (int i = 1; i < 4; ++i) mx = fmaxf(mx, sH[0][i]);
#pragma unroll
            for (int i = 0; i < 4; ++i) mx = fmaxf(mx, sH[1][i]);
            mx = fmaxf(mx, __shfl_xor(mx, 16));
            mx = fmaxf(mx, __shfl_xor(mx, 32));
            const float mn = fmaxf(mH, mx);
            aH = exp2f(mH - mn);
            mH = mn;
            float rs = 0.f;
#pragma unroll
            for (int t = 0; t < 2; ++t)
#pragma unroll
                for (int i = 0; i < 4; ++i) {
                    const float p = exp2f(sH[t][i] - mn);
                    sH[t][i] = p;
                    rs += p;
                }
            rs += __shfl_xor(rs, 16);
            rs += __shfl_xor(rs, 32);
            lH = lH * aH + rs;
            // P^T row q=l16: keys t*16+quad*4+i  (one b64 store per subtile)
#pragma unroll
            for (int t = 0; t < 2; ++t) {
                bf16x4 pk = {(__bf16)sH[t][0], (__bf16)sH[t][1],
                             (__bf16)sH[t][2], (__bf16)sH[t][3]};
                *(bf16x4*)&Ps[wave][0][l16][t * 16 + quad * 4] = pk;
            }
        }

        // ---- lo group (predicated) ----
        float aL = 1.f;
        if (do_lo) {
            if (k0 + 31 > q_lo) {
#pragma unroll
                for (int t = 0; t < 2; ++t)
#pragma unroll
                    for (int i = 0; i < 4; ++i)
                        sL[t][i] = (k0 + t * 16 + quad * 4 + i <= q_lo + l16)
                                   ? sL[t][i] : -1e30f;
            }
            float mx = sL[0][0];
#pragma unroll
            for (int i = 1; i < 4; ++i) mx = fmaxf(mx, sL[0][i]);
#pragma unroll
            for (int i = 0; i < 4; ++i) mx = fmaxf(mx, sL[1][i]);
            mx = fmaxf(mx, __shfl_xor(mx, 16));
            mx = fmaxf(mx, __shfl_xor(mx, 32));
            const float mn = fmaxf(mL, mx);
            aL = exp2f(mL - mn);
            mL = mn;
            float rs = 0.f;
#pragma unroll
            for (int t = 0; t < 2; ++t)
#pragma unroll
                for (int i = 0; i < 4; ++i) {
                    const float p = exp2f(sL[t][i] - mn);
                    sL[t][i] = p;
                    rs += p;
                }
            rs += __shfl_xor(rs, 16);
            rs += __shfl_xor(rs, 32);
            lL = lL * aL + rs;
#pragma unroll
            for (int t = 0; t < 2; ++t) {
                bf16x4 pk = {(__bf16)sL[t][0], (__bf16)sL[t][1],
                             (__bf16)sL[t][2], (__bf16)sL[t][3]};
                *(bf16x4*)&Ps[wave][1][l16][t * 16 + quad * 4] = pk;
            }
        }

        // V fragments (A operand: A[m=d][k=key]) — issue before the LDS wait
        bf16x8 vf[5];
#pragma unroll
        for (int t = 0; t < 5; ++t)
            vf[t] = *(const bf16x8*)(Vbase + (size_t)(t * 16 + l16) * S_ + k0 + quad * 8);

        asm volatile("s_waitcnt lgkmcnt(0)" ::: "memory");
        const bf16x8 pfH = *(const bf16x8*)&Ps[wave][0][l16][quad * 8];
        const bf16x8 pfL = *(const bf16x8*)&Ps[wave][1][l16][quad * 8];

        // ---- O^T = O^T*alpha + Vt·P^T : 5 dim-subtiles, K=32 keys ----
#pragma unroll
        for (int t = 0; t < 5; ++t) {
            f32x4 c;
#pragma unroll
            for (int i = 0; i < 4; ++i) c[i] = oH[t][i] * aH;
            oH[t] = __builtin_amdgcn_mfma_f32_16x16x32_bf16(vf[t], pfH, c, 0, 0, 0);
            if (do_lo) {
                f32x4 d;
#pragma unroll
                for (int i = 0; i < 4; ++i) d[i] = oL[t][i] * aL;
                oL[t] = __builtin_amdgcn_mfma_f32_16x16x32_bf16(vf[t], pfL, d, 0, 0, 0);
            }
        }
    }

    // ---- epilogue: O^T C-layout -> packed 8B stores (4 dims per lane) ----
    const float invH = 1.f / lH;
    const float invL = 1.f / lL;
    const size_t rowH = ((size_t)b * S_ + q_hi + l16) * HHD + h * HD_ + quad * 4;
    const size_t rowL = ((size_t)b * S_ + q_lo + l16) * HHD + h * HD_ + quad * 4;
#pragma unroll
    for (int t = 0; t < 5; ++t) {
        bf16x4 ovH = {(__bf16)(oH[t][0] * invH), (__bf16)(oH[t][1] * invH),
                      (__bf16)(oH[t][2] * invH), (__bf16)(oH[t][3] * invH)};
        bf16x4 ovL = {(__bf16)(oL[t][0] * invL), (__bf16)(oL[t][1] * invL),
                      (__bf16)(oL[t][2] * invL), (__bf16)(oL[t][3] * invL)};
        *(bf16x4*)(out + rowH + t * 16) = ovH;
        *(bf16x4*)(out + rowL + t * 16) = ovL;
    }
}

// ---------------------------------------------------------------------------
extern "C" void kernel_launch(void* const* d_in, const int* in_sizes, int n_in,
                              void* d_out, int out_size, void* d_ws, size_t ws_size,
                              hipStream_t stream)
{
    const float* hidden  = (const float*)d_in[0];
    // d_in[1] attention_mask: exact additive causal (-1e9) — replicated
    // structurally in attn_v7 (exp underflow makes it bit-identical).
    const float* scaling = (const float*)d_in[2];
    const float* qkv_w   = (const float*)d_in[3];
    const float* qkv_b   = (const float*)d_in[4];
    const float* o_w     = (const float*)d_in[5];
    const float* o_b     = (const float*)d_in[6];
    float* out = (float*)d_out;

    const size_t N_HID = (size_t)B_ * S_ * D_;
    const size_t N_QW  = (size_t)QKVN * D_;
    const size_t N_OW  = (size_t)D_ * D_;
    const size_t NPH   = (size_t)B_ * H_ * S_ * HD_;

    __bf16* Ab    = (__bf16*)d_ws;
    __bf16* Wqb   = Ab + N_HID;
    __bf16* Wob   = Wqb + N_QW;
    __bf16* Qb    = Wob + N_OW;
    __bf16* Kb    = Qb + NPH;
    __bf16* Vtb   = Kb + NPH;
    __bf16* attnb = Vtb + NPH;

    dim3 blk(256);

    cvt_bf16<<<dim3(N_HID / 8 / 256), blk, 0, stream>>>(hidden, Ab, N_HID / 8);
    cvt_bf16<<<dim3(N_QW  / 8 / 256), blk, 0, stream>>>(qkv_w, Wqb, N_QW / 8);
    cvt_bf16<<<dim3(N_OW  / 8 / 256), blk, 0, stream>>>(o_w,   Wob, N_OW / 8);

    gemm_qkv_mfma<<<dim3(QKVN / 128, B_ * S_ / 128), blk, 0, stream>>>(
        Ab, Wqb, qkv_b, scaling, Qb, Kb, Vtb);

    attn_v7<<<dim3(16, H_, B_), blk, 0, stream>>>(Qb, Kb, Vtb, attnb);

    gemm_o_mfma<<<dim3(D_ / 128, B_ * S_ / 128), blk, 0, stream>>>(
        attnb, Wob, o_b, out);
}